// Round 7
// baseline (954.294 us; speedup 1.0000x reference)
//
#include <hip/hip_runtime.h>

// FourierBlock: per (b, c): rfft(4096) -> keep top-16 |X| bins -> irfft.
//
// Round 10: 512-thread / 33 KB radix-8 structure kept, two fixes from the
// round-6 post-mortem:
//  (1) __launch_bounds__ second arg behaves like CUDA min-BLOCKS-per-CU on
//      this toolchain (evidence: (512,8) -> 32-VGPR cap -> synth spilled,
//      ~970 MB scratch traffic; (256,4) -> 64). So (512,4) = 4 blocks/CU =
//      8 waves/SIMD = 64-VGPR cap = 32 waves/CU, double round-5 streams.
//  (2) Block owns 4 CHANNELS with float4 loads/stores (round 4 measured
//      WRITE_SIZE == 131072 KB exactly -> 8 siblings/cacheline merge
//      perfectly in L2), instead of round-5/6's float2 pairs (405 MB, 3x
//      write amplification). The two complex FFTs run SEQUENTIALLY over one
//      32 KB LDS buffer; channels 2/3 park in 16 registers during FFT #1.
//  Register budget engineered for the 64 cap: synth accumulates acc[8][4]
//  (32 regs, ch-loop unrolled -> static indexing) with bins in groups of 4
//  (u/v/T[4] = 12 transient regs); top-k path ~60 live incl. the 16 parked.

#define SWZ(i) ((i) ^ (((i) >> 4) & 15))

__device__ __forceinline__ int drev8(int x) {
  // reverse the four octal digits of a 12-bit index (involution)
  return ((x & 7) << 9) | ((x & 0x38) << 3) | ((x >> 3) & 0x38) | ((x >> 9) & 7);
}

__device__ __forceinline__ float2 cmulf(float2 a, float c, float s) {
  return make_float2(a.x * c - a.y * s, a.x * s + a.y * c);
}

__device__ __forceinline__ float2 cadd(float2 a, float2 b) { return make_float2(a.x + b.x, a.y + b.y); }
__device__ __forceinline__ float2 csub(float2 a, float2 b) { return make_float2(a.x - b.x, a.y - b.y); }
__device__ __forceinline__ float2 cmulnegi(float2 a) { return make_float2(a.y, -a.x); }      // a * (-i)
__device__ __forceinline__ float2 cmulposi(float2 a) { return make_float2(-a.y, a.x); }      // a * (+i)

// 8-point DFT in registers, natural-order input AND output.
// X[r] = sum_k a[k] e^{-2 pi i r k / 8}.
__device__ __forceinline__ void dft8(float2* a) {
  const float R = 0.7071067811865476f;
  float2 t0 = cadd(a[0], a[4]), t1 = cadd(a[1], a[5]);
  float2 t2 = cadd(a[2], a[6]), t3 = cadd(a[3], a[7]);
  float2 u0 = csub(a[0], a[4]);
  float2 d1 = csub(a[1], a[5]);
  float2 u1 = make_float2(R * (d1.x + d1.y), R * (d1.y - d1.x));   // * W8^1
  float2 u2 = cmulnegi(csub(a[2], a[6]));                          // * W8^2
  float2 d3 = csub(a[3], a[7]);
  float2 u3 = make_float2(R * (d3.y - d3.x), R * (-(d3.x + d3.y))); // * W8^3
  {
    float2 b0 = cadd(t0, t2), b1 = csub(t0, t2);
    float2 b2 = cadd(t1, t3), b3 = csub(t1, t3);
    a[0] = cadd(b0, b2);
    a[2] = cadd(b1, cmulnegi(b3));
    a[4] = csub(b0, b2);
    a[6] = cadd(b1, cmulposi(b3));
  }
  {
    float2 b0 = cadd(u0, u2), b1 = csub(u0, u2);
    float2 b2 = cadd(u1, u3), b3 = csub(u1, u3);
    a[1] = cadd(b0, b2);
    a[3] = cadd(b1, cmulnegi(b3));
    a[5] = csub(b0, b2);
    a[7] = cadd(b1, cmulposi(b3));
  }
}

// One radix-8 DIF pass. M = current span; M=8 -> last pass, no twiddle.
// Twiddle angle j*r/M revolutions: exact fp32, in [0,1) -> v_sin/v_cos.
template <int STRIDE, int M>
__device__ __forceinline__ void fft_pass8(float2* Zl, int base, int j) {
  float2 v[8];
  #pragma unroll
  for (int p = 0; p < 8; p++) v[p] = Zl[SWZ(base + j + STRIDE * p)];
  dft8(v);
  #pragma unroll
  for (int r = 1; r < 8; r++) {
    if (M > 8) {
      int a = j * r;                                // < M
      float x = (float)a * (1.0f / (float)M);       // revolutions, exact
      float s = -__builtin_amdgcn_sinf(x);          // e^{-2 pi i x}
      float c =  __builtin_amdgcn_cosf(x);
      v[r] = cmulf(v[r], c, s);
    }
  }
  #pragma unroll
  for (int r = 0; r < 8; r++) Zl[SWZ(base + j + STRIDE * r)] = v[r];
}

// ---------------- fused FFT + top-k + synthesis kernel ---------------------

__global__ __launch_bounds__(512, 4) void fourier_fused(
    const float4* __restrict__ X4, float4* __restrict__ O4) {
  __shared__ float2 Z[4096];        // one complex FFT workspace (32 KB)
  __shared__ float4 CF[64];         // [gc*16+j] = (a, b, cos_step, sin_step)
  __shared__ float  CFf[64];        // bin frequency f

  const int tid = threadIdx.x;
  // XCD-contiguous remap (bijective: 2048 blocks, 8 XCDs, 256 each):
  // XCD k gets original ids [256k, 256k+256) -> 8 whole batches per XCD,
  // so the 32 sibling blocks of a batch run on one XCD and merge their
  // strided float4 reads/writes in that XCD's L2.
  const int o = ((blockIdx.x & 7) << 8) + (blockIdx.x >> 3);
  const int b = o >> 5;
  const int q = o & 31;             // 4-channel group: channels 4q..4q+3

  const int wv = tid >> 6;          // wave index 0..7
  const int lane = tid & 63;

  // ---- load: x[b, l, 4q..4q+3] = one float4. (ch0,ch1) -> Z now;
  //      (ch2,ch3) park in 16 registers until FFT #2.
  const float4* src = X4 + (size_t)b * 4096 * 32 + q;
  float pr[8], pi[8];
  #pragma unroll
  for (int k = 0; k < 8; k++) {
    int l = tid + 512 * k;
    float4 v = src[(size_t)l * 32];
    Z[SWZ(l)] = make_float2(v.x, v.y);
    pr[k] = v.z;
    pi[k] = v.w;
  }
  __syncthreads();

  // ---- two sequential {FFT, top-k} halves over the same Z ----
  #pragma unroll 1
  for (int half = 0; half < 2; half++) {
    if (half) {                     // Z dead after top-k #0: load parked pair
      #pragma unroll
      for (int k = 0; k < 8; k++) Z[SWZ(tid + 512 * k)] = make_float2(pr[k], pi[k]);
      __syncthreads();
    }

    // forward FFT: 4 radix-8 DIF passes; slot p ends holding bin drev8(p)
    fft_pass8<512, 4096>(Z, 0, tid);
    __syncthreads();
    fft_pass8<64, 512>(Z, (tid >> 6) << 9, tid & 63);
    __syncthreads();
    fft_pass8<8, 64>(Z, (tid >> 3) << 6, tid & 7);
    __syncthreads();
    fft_pass8<1, 8>(Z, tid << 3, 0);
    __syncthreads();

    // top-16: wave 0 = even channel of this half, wave 1 = odd channel
    if (wv < 2) {
      const int ch = wv;
      int rF = 0; float rA = 0.f, rB = 0.f;   // winner (lanes 0..15)
      float m2[32];
      #pragma unroll
      for (int k = 0; k < 32; k++) {
        int f = lane + (k << 6);
        float2 P = Z[SWZ(drev8(f))];
        float2 Q = Z[SWZ(drev8((4096 - f) & 4095))];
        float xr = ch ? (P.y + Q.y) : (P.x + Q.x);
        float xi = ch ? (Q.x - P.x) : (P.y - Q.y);
        m2[k] = xr * xr + xi * xi;   // 4*|X|^2 (ordering only)
      }
      float m2x = -1.f;              // bin f=2048 (Nyquist), lane 0 only
      if (lane == 0) {
        float2 P = Z[SWZ(4)];        // drev8(2048) == 4
        float t = ch ? P.y : P.x;
        m2x = 4.f * t * t;
      }
      for (int r = 0; r < 16; r++) {
        float bv = -1e30f; int bf = 0;
        #pragma unroll
        for (int k = 0; k < 32; k++) {
          int f = lane + (k << 6);
          if (m2[k] > bv) { bv = m2[k]; bf = f; }   // ties -> lower f
        }
        if (m2x > bv) { bv = m2x; bf = 2048; }
        #pragma unroll
        for (int off = 32; off; off >>= 1) {
          float ov = __shfl_down(bv, off);
          int   of = __shfl_down(bf, off);
          if (ov > bv || (ov == bv && of < bf)) { bv = ov; bf = of; }
        }
        bf = __shfl(bf, 0);          // broadcast winner bin
        if (lane == r) {             // capture X[bf] in lane r
          rF = bf;
          float2 P = Z[SWZ(drev8(bf))];
          float2 Q = Z[SWZ(drev8((4096 - bf) & 4095))];
          rA = ch ? 0.5f * (P.y + Q.y) : 0.5f * (P.x + Q.x);
          rB = ch ? 0.5f * (Q.x - P.x) : 0.5f * (P.y - Q.y);
        }
        if (bf == 2048) {
          if (lane == 0) m2x = -2.f;
        } else if ((bf & 63) == lane) {
          int kk = bf >> 6;
          #pragma unroll
          for (int k = 0; k < 32; k++) if (k == kk) m2[k] = -2.f;
        }
      }

      // publish coefficients + stride-512 step constants.
      // out[l] = sum alpha*cos(2 pi f l/4096) + beta*sin(...), with
      // alpha = w*Re(X), beta = -w*Im(X), w = 1/N (f=0,2048) else 2/N.
      // Step angle f*512/4096 = f/8 rev (exact fp32).
      if (lane < 16) {
        const float inv = 2.44140625e-4f;            // 1/4096
        float w = (rF == 0 || rF == 2048) ? inv : 2.f * inv;
        float fv = (float)rF;
        float dx = fv * 0.125f;
        dx -= floorf(dx);
        float cd = __builtin_amdgcn_cosf(dx);
        float sd = __builtin_amdgcn_sinf(dx);
        int gc = half * 2 + ch;                      // block channel 0..3
        CF[gc * 16 + lane] = make_float4(w * rA, -w * rB, cd, sd);
        CFf[gc * 16 + lane] = fv;
      }
    }
    __syncthreads();   // spectrum consumed; CF[half] published
  }

  // ---- synthesis: thread owns samples l = tid + 512k, k = 0..7, 4 ch.
  // Chebyshev: g(l+512) = T g(l) - g(l-512), T = 2 cos(2 pi f/8).
  // acc[k][ch] (32 regs) statically indexed: ch loop unrolled; bins in
  // groups of 4 (u/v/T[4] transient). x0 = f*tid/4096 rev exact.
  float acc[8][4];
  #pragma unroll
  for (int k = 0; k < 8; k++)
    #pragma unroll
    for (int c = 0; c < 4; c++) acc[k][c] = 0.f;

  const float tf = (float)tid;
  #pragma unroll
  for (int ch = 0; ch < 4; ch++) {
    #pragma unroll 1
    for (int g = 0; g < 4; g++) {
      float u[4], v[4], T[4];
      #pragma unroll
      for (int j = 0; j < 4; j++) {
        float4 cf = CF[ch * 16 + g * 4 + j];
        float f  = CFf[ch * 16 + g * 4 + j];
        float x0 = f * tf * 2.44140625e-4f;
        x0 -= floorf(x0);
        float c0 = __builtin_amdgcn_cosf(x0);
        float s0 = __builtin_amdgcn_sinf(x0);
        float G = fmaf(cf.x, c0, cf.y * s0);    // g(tid)
        float H = fmaf(cf.y, c0, -cf.x * s0);   // b cos - a sin
        u[j] = G;
        v[j] = fmaf(G, cf.z, -H * cf.w);        // g(tid - 512)
        T[j] = cf.z + cf.z;
      }
      #pragma unroll
      for (int k = 0; k < 8; k += 2) {
        #pragma unroll
        for (int j = 0; j < 4; j++) {
          acc[k][ch] += u[j];
          v[j] = fmaf(T[j], u[j], -v[j]);       // v <- g(l + 512)
        }
        #pragma unroll
        for (int j = 0; j < 4; j++) {
          acc[k + 1][ch] += v[j];
          u[j] = fmaf(T[j], v[j], -u[j]);       // u <- g(l + 1024)
        }
      }
    }
  }

  // ---- store: float4 = 4 channels at one sample, mirror of the load ----
  float4* dst = O4 + (size_t)b * 4096 * 32 + q;
  #pragma unroll
  for (int k = 0; k < 8; k++) {
    int l = tid + 512 * k;
    dst[(size_t)l * 32] = make_float4(acc[k][0], acc[k][1], acc[k][2], acc[k][3]);
  }
}

extern "C" void kernel_launch(void* const* d_in, const int* in_sizes, int n_in,
                              void* d_out, int out_size, void* d_ws, size_t ws_size,
                              hipStream_t stream) {
  (void)in_sizes; (void)n_in; (void)ws_size; (void)out_size; (void)d_ws;
  const float4* x = (const float4*)d_in[0];
  float4* out = (float4*)d_out;

  fourier_fused<<<dim3(64 * 32), dim3(512), 0, stream>>>(x, out);
}

// Round 8
// 950.222 us; speedup vs baseline: 1.0043x; 1.0043x over previous
//
#include <hip/hip_runtime.h>

// FourierBlock: per (b, c): rfft(4096) -> keep top-16 |X| bins -> irfft.
//
// Round 11: round-10 structure (512 threads, radix-8 FFT over one 32 KB LDS
// spectrum, 4 channels/block, float4 merged stores, (512,4) -> 64-VGPR cap,
// 32 waves/CU) with the register-spill fixed. Round-10 spilled (~1.7 GB
// scratch traffic, VALUBusy 17%) because channels 2/3 were PARKED in 16
// VGPRs across FFT#1 AND top-k (peak ~70 > 64 cap). Fix: don't park —
// RELOAD ch2/3 from global at the start of half 1 (float2 loads on the same
// sibling-merged cachelines; the 128 MB input is L3-resident, so the second
// pass is an L3 hit and overlaps across 32 waves/CU). Register audit
// without parking: FFT pass ~26, top-k ~45 (m2[32]+temps), synth ~52
// (acc[8][4]=32 + u/v/T[4]=12) -> peak ~55 < 64.

#define SWZ(i) ((i) ^ (((i) >> 4) & 15))

__device__ __forceinline__ int drev8(int x) {
  // reverse the four octal digits of a 12-bit index (involution)
  return ((x & 7) << 9) | ((x & 0x38) << 3) | ((x >> 3) & 0x38) | ((x >> 9) & 7);
}

__device__ __forceinline__ float2 cmulf(float2 a, float c, float s) {
  return make_float2(a.x * c - a.y * s, a.x * s + a.y * c);
}

__device__ __forceinline__ float2 cadd(float2 a, float2 b) { return make_float2(a.x + b.x, a.y + b.y); }
__device__ __forceinline__ float2 csub(float2 a, float2 b) { return make_float2(a.x - b.x, a.y - b.y); }
__device__ __forceinline__ float2 cmulnegi(float2 a) { return make_float2(a.y, -a.x); }      // a * (-i)
__device__ __forceinline__ float2 cmulposi(float2 a) { return make_float2(-a.y, a.x); }      // a * (+i)

// 8-point DFT in registers, natural-order input AND output.
// X[r] = sum_k a[k] e^{-2 pi i r k / 8}.
__device__ __forceinline__ void dft8(float2* a) {
  const float R = 0.7071067811865476f;
  float2 t0 = cadd(a[0], a[4]), t1 = cadd(a[1], a[5]);
  float2 t2 = cadd(a[2], a[6]), t3 = cadd(a[3], a[7]);
  float2 u0 = csub(a[0], a[4]);
  float2 d1 = csub(a[1], a[5]);
  float2 u1 = make_float2(R * (d1.x + d1.y), R * (d1.y - d1.x));   // * W8^1
  float2 u2 = cmulnegi(csub(a[2], a[6]));                          // * W8^2
  float2 d3 = csub(a[3], a[7]);
  float2 u3 = make_float2(R * (d3.y - d3.x), R * (-(d3.x + d3.y))); // * W8^3
  {
    float2 b0 = cadd(t0, t2), b1 = csub(t0, t2);
    float2 b2 = cadd(t1, t3), b3 = csub(t1, t3);
    a[0] = cadd(b0, b2);
    a[2] = cadd(b1, cmulnegi(b3));
    a[4] = csub(b0, b2);
    a[6] = cadd(b1, cmulposi(b3));
  }
  {
    float2 b0 = cadd(u0, u2), b1 = csub(u0, u2);
    float2 b2 = cadd(u1, u3), b3 = csub(u1, u3);
    a[1] = cadd(b0, b2);
    a[3] = cadd(b1, cmulnegi(b3));
    a[5] = csub(b0, b2);
    a[7] = cadd(b1, cmulposi(b3));
  }
}

// One radix-8 DIF pass. M = current span; M=8 -> last pass, no twiddle.
// Twiddle angle j*r/M revolutions: exact fp32, in [0,1) -> v_sin/v_cos.
template <int STRIDE, int M>
__device__ __forceinline__ void fft_pass8(float2* Zl, int base, int j) {
  float2 v[8];
  #pragma unroll
  for (int p = 0; p < 8; p++) v[p] = Zl[SWZ(base + j + STRIDE * p)];
  dft8(v);
  #pragma unroll
  for (int r = 1; r < 8; r++) {
    if (M > 8) {
      int a = j * r;                                // < M
      float x = (float)a * (1.0f / (float)M);       // revolutions, exact
      float s = -__builtin_amdgcn_sinf(x);          // e^{-2 pi i x}
      float c =  __builtin_amdgcn_cosf(x);
      v[r] = cmulf(v[r], c, s);
    }
  }
  #pragma unroll
  for (int r = 0; r < 8; r++) Zl[SWZ(base + j + STRIDE * r)] = v[r];
}

// ---------------- fused FFT + top-k + synthesis kernel ---------------------

__global__ __launch_bounds__(512, 4) void fourier_fused(
    const float2* __restrict__ X2, float4* __restrict__ O4) {
  __shared__ float2 Z[4096];        // one complex FFT workspace (32 KB)
  __shared__ float4 CF[64];         // [gc*16+j] = (a, b, cos_step, sin_step)
  __shared__ float  CFf[64];        // bin frequency f

  const int tid = threadIdx.x;
  // XCD-contiguous remap (bijective: 2048 blocks, 8 XCDs, 256 each):
  // XCD k gets original ids [256k, 256k+256) -> 8 whole batches per XCD,
  // so the 32 sibling blocks of a batch run on one XCD and merge their
  // strided reads/writes in that XCD's L2.
  const int o = ((blockIdx.x & 7) << 8) + (blockIdx.x >> 3);
  const int b = o >> 5;
  const int q = o & 31;             // 4-channel group: channels 4q..4q+3

  const int wv = tid >> 6;          // wave index 0..7
  const int lane = tid & 63;

  // src points at channel pair (4q, 4q+1); +1 selects pair (4q+2, 4q+3).
  const float2* src = X2 + (size_t)b * 4096 * 64 + 2 * q;

  // ---- two sequential {load, FFT, top-k} halves over the same Z ----
  #pragma unroll 1
  for (int half = 0; half < 2; half++) {
    // load channel pair of this half: x[b, l, 4q+2*half .. +1] = one float2.
    // Half 1 re-reads from global (L3-resident; no registers parked).
    #pragma unroll
    for (int k = 0; k < 8; k++) {
      int l = tid + 512 * k;
      Z[SWZ(l)] = src[(size_t)l * 64 + half];
    }
    __syncthreads();

    // forward FFT: 4 radix-8 DIF passes; slot p ends holding bin drev8(p)
    fft_pass8<512, 4096>(Z, 0, tid);
    __syncthreads();
    fft_pass8<64, 512>(Z, (tid >> 6) << 9, tid & 63);
    __syncthreads();
    fft_pass8<8, 64>(Z, (tid >> 3) << 6, tid & 7);
    __syncthreads();
    fft_pass8<1, 8>(Z, tid << 3, 0);
    __syncthreads();

    // top-16: wave 0 = even channel of this half, wave 1 = odd channel
    if (wv < 2) {
      const int ch = wv;
      int rF = 0; float rA = 0.f, rB = 0.f;   // winner (lanes 0..15)
      float m2[32];
      #pragma unroll
      for (int k = 0; k < 32; k++) {
        int f = lane + (k << 6);
        float2 P = Z[SWZ(drev8(f))];
        float2 Q = Z[SWZ(drev8((4096 - f) & 4095))];
        float xr = ch ? (P.y + Q.y) : (P.x + Q.x);
        float xi = ch ? (Q.x - P.x) : (P.y - Q.y);
        m2[k] = xr * xr + xi * xi;   // 4*|X|^2 (ordering only)
      }
      float m2x = -1.f;              // bin f=2048 (Nyquist), lane 0 only
      if (lane == 0) {
        float2 P = Z[SWZ(4)];        // drev8(2048) == 4
        float t = ch ? P.y : P.x;
        m2x = 4.f * t * t;
      }
      for (int r = 0; r < 16; r++) {
        float bv = -1e30f; int bf = 0;
        #pragma unroll
        for (int k = 0; k < 32; k++) {
          int f = lane + (k << 6);
          if (m2[k] > bv) { bv = m2[k]; bf = f; }   // ties -> lower f
        }
        if (m2x > bv) { bv = m2x; bf = 2048; }
        #pragma unroll
        for (int off = 32; off; off >>= 1) {
          float ov = __shfl_down(bv, off);
          int   of = __shfl_down(bf, off);
          if (ov > bv || (ov == bv && of < bf)) { bv = ov; bf = of; }
        }
        bf = __shfl(bf, 0);          // broadcast winner bin
        if (lane == r) {             // capture X[bf] in lane r
          rF = bf;
          float2 P = Z[SWZ(drev8(bf))];
          float2 Q = Z[SWZ(drev8((4096 - bf) & 4095))];
          rA = ch ? 0.5f * (P.y + Q.y) : 0.5f * (P.x + Q.x);
          rB = ch ? 0.5f * (Q.x - P.x) : 0.5f * (P.y - Q.y);
        }
        if (bf == 2048) {
          if (lane == 0) m2x = -2.f;
        } else if ((bf & 63) == lane) {
          int kk = bf >> 6;
          #pragma unroll
          for (int k = 0; k < 32; k++) if (k == kk) m2[k] = -2.f;
        }
      }

      // publish coefficients + stride-512 step constants.
      // out[l] = sum alpha*cos(2 pi f l/4096) + beta*sin(...), with
      // alpha = w*Re(X), beta = -w*Im(X), w = 1/N (f=0,2048) else 2/N.
      // Step angle f*512/4096 = f/8 rev (exact fp32).
      if (lane < 16) {
        const float inv = 2.44140625e-4f;            // 1/4096
        float w = (rF == 0 || rF == 2048) ? inv : 2.f * inv;
        float fv = (float)rF;
        float dx = fv * 0.125f;
        dx -= floorf(dx);
        float cd = __builtin_amdgcn_cosf(dx);
        float sd = __builtin_amdgcn_sinf(dx);
        int gc = half * 2 + ch;                      // block channel 0..3
        CF[gc * 16 + lane] = make_float4(w * rA, -w * rB, cd, sd);
        CFf[gc * 16 + lane] = fv;
      }
    }
    __syncthreads();   // all Z readers done; CF[half] published
  }

  // ---- synthesis: thread owns samples l = tid + 512k, k = 0..7, 4 ch.
  // Chebyshev: g(l+512) = T g(l) - g(l-512), T = 2 cos(2 pi f/8).
  // acc[k][ch] (32 regs) statically indexed: ch loop unrolled; bins in
  // groups of 4 (u/v/T[4] transient). x0 = f*tid/4096 rev exact.
  float acc[8][4];
  #pragma unroll
  for (int k = 0; k < 8; k++)
    #pragma unroll
    for (int c = 0; c < 4; c++) acc[k][c] = 0.f;

  const float tf = (float)tid;
  #pragma unroll
  for (int ch = 0; ch < 4; ch++) {
    #pragma unroll 1
    for (int g = 0; g < 4; g++) {
      float u[4], v[4], T[4];
      #pragma unroll
      for (int j = 0; j < 4; j++) {
        float4 cf = CF[ch * 16 + g * 4 + j];
        float f  = CFf[ch * 16 + g * 4 + j];
        float x0 = f * tf * 2.44140625e-4f;
        x0 -= floorf(x0);
        float c0 = __builtin_amdgcn_cosf(x0);
        float s0 = __builtin_amdgcn_sinf(x0);
        float G = fmaf(cf.x, c0, cf.y * s0);    // g(tid)
        float H = fmaf(cf.y, c0, -cf.x * s0);   // b cos - a sin
        u[j] = G;
        v[j] = fmaf(G, cf.z, -H * cf.w);        // g(tid - 512)
        T[j] = cf.z + cf.z;
      }
      #pragma unroll
      for (int k = 0; k < 8; k += 2) {
        #pragma unroll
        for (int j = 0; j < 4; j++) {
          acc[k][ch] += u[j];
          v[j] = fmaf(T[j], u[j], -v[j]);       // v <- g(l + 512)
        }
        #pragma unroll
        for (int j = 0; j < 4; j++) {
          acc[k + 1][ch] += v[j];
          u[j] = fmaf(T[j], v[j], -u[j]);       // u <- g(l + 1024)
        }
      }
    }
  }

  // ---- store: float4 = 4 channels at one sample, sibling-merged lines ----
  float4* dst = O4 + (size_t)b * 4096 * 32 + q;
  #pragma unroll
  for (int k = 0; k < 8; k++) {
    int l = tid + 512 * k;
    dst[(size_t)l * 32] = make_float4(acc[k][0], acc[k][1], acc[k][2], acc[k][3]);
  }
}

extern "C" void kernel_launch(void* const* d_in, const int* in_sizes, int n_in,
                              void* d_out, int out_size, void* d_ws, size_t ws_size,
                              hipStream_t stream) {
  (void)in_sizes; (void)n_in; (void)ws_size; (void)out_size; (void)d_ws;
  const float2* x = (const float2*)d_in[0];
  float4* out = (float4*)d_out;

  fourier_fused<<<dim3(64 * 32), dim3(512), 0, stream>>>(x, out);
}

// Round 9
// 703.505 us; speedup vs baseline: 1.3565x; 1.3507x over previous
//
#include <hip/hip_runtime.h>

// FourierBlock: per (b, c): rfft(4096) -> keep top-16 |X| bins -> irfft.
//
// Round 12: occupancy via LDS, not VGPR caps. Rounds 6 vs 8 ran identical
// (spilled) code at occ 84% -> 449 us and occ 42% -> 852 us: dur*occ const
// to 3% -> the kernel family is purely latency-bound, dur ~ 1/occupancy.
// Every spill came from hard-capping VGPR below true demand (~80). So:
//  - Halve LDS per channel with the classic real-FFT trick: one channel's
//    even/odd samples = re/im of a 2048-pt complex FFT (16 KB), untangled
//    on the fly in the top-k scan (X[f] = E + W^f O, 2 LDS reads + 1
//    sincos/bin). In float2-complex layout the even/odd packing IS the
//    natural sample order, so loads are unchanged.
//  - 256-thread block, 2 channels SEQUENTIALLY over one 16.5 KB buffer
//    (mixed radix 8*8*8*4, slot map = round-7's verified drev8 pattern).
//    LDS allows 8 blocks/CU = 32 waves/CU (2x round 5).
//  - Register demand cut structurally: top-k is 4-wave cooperative (m2[8]
//    + tiny LDS reduce, was m2[32]); synth stages ch0 through dead
//    spectrum LDS. Peak ~45-50.
//  - __launch_bounds__(256, 4): cap 128 -> NO forced spill; worst case
//    VGPR 65-73 gives 7 blocks instead of 8.

#define SWZ(i) ((i) ^ (((i) >> 4) & 15))

// mixed-radix (8,8,8,4) DIF slot of bin f: slot = r1*256 + r2*32 + r3*4 + p
// where f = r1 + 8*r2 + 64*r3 + 512*p  (same digit-reversal scheme as the
// verified radix-8 drev8 of rounds 9-11).
__device__ __forceinline__ int slotOf(int f) {
  return ((f & 7) << 8) | (((f >> 3) & 7) << 5) | (((f >> 6) & 7) << 2) | ((f >> 9) & 3);
}

__device__ __forceinline__ float2 cmulf(float2 a, float c, float s) {
  return make_float2(a.x * c - a.y * s, a.x * s + a.y * c);
}

__device__ __forceinline__ float2 cadd(float2 a, float2 b) { return make_float2(a.x + b.x, a.y + b.y); }
__device__ __forceinline__ float2 csub(float2 a, float2 b) { return make_float2(a.x - b.x, a.y - b.y); }
__device__ __forceinline__ float2 cmulnegi(float2 a) { return make_float2(a.y, -a.x); }      // a * (-i)
__device__ __forceinline__ float2 cmulposi(float2 a) { return make_float2(-a.y, a.x); }      // a * (+i)

// 8-point DFT in registers, natural-order input AND output.
__device__ __forceinline__ void dft8(float2* a) {
  const float R = 0.7071067811865476f;
  float2 t0 = cadd(a[0], a[4]), t1 = cadd(a[1], a[5]);
  float2 t2 = cadd(a[2], a[6]), t3 = cadd(a[3], a[7]);
  float2 u0 = csub(a[0], a[4]);
  float2 d1 = csub(a[1], a[5]);
  float2 u1 = make_float2(R * (d1.x + d1.y), R * (d1.y - d1.x));   // * W8^1
  float2 u2 = cmulnegi(csub(a[2], a[6]));                          // * W8^2
  float2 d3 = csub(a[3], a[7]);
  float2 u3 = make_float2(R * (d3.y - d3.x), R * (-(d3.x + d3.y))); // * W8^3
  {
    float2 b0 = cadd(t0, t2), b1 = csub(t0, t2);
    float2 b2 = cadd(t1, t3), b3 = csub(t1, t3);
    a[0] = cadd(b0, b2);
    a[2] = cadd(b1, cmulnegi(b3));
    a[4] = csub(b0, b2);
    a[6] = cadd(b1, cmulposi(b3));
  }
  {
    float2 b0 = cadd(u0, u2), b1 = csub(u0, u2);
    float2 b2 = cadd(u1, u3), b3 = csub(u1, u3);
    a[1] = cadd(b0, b2);
    a[3] = cadd(b1, cmulnegi(b3));
    a[5] = csub(b0, b2);
    a[7] = cadd(b1, cmulposi(b3));
  }
}

// 4-point DFT, natural order.
__device__ __forceinline__ void dft4i(float2* a) {
  float2 t0 = cadd(a[0], a[2]), t1 = csub(a[0], a[2]);
  float2 t2 = cadd(a[1], a[3]), t3 = csub(a[1], a[3]);
  a[0] = cadd(t0, t2);
  a[1] = cadd(t1, cmulnegi(t3));
  a[2] = csub(t0, t2);
  a[3] = csub(t1, cmulnegi(t3));
}

// One radix-8 DIF pass; twiddle W_M^{j*r}. Angle j*r/M rev: exact fp32,
// already in [0,1) -> v_sin/v_cos directly.
template <int STRIDE, int M>
__device__ __forceinline__ void fft_pass8(float2* Zl, int base, int j) {
  float2 v[8];
  #pragma unroll
  for (int p = 0; p < 8; p++) v[p] = Zl[SWZ(base + j + STRIDE * p)];
  dft8(v);
  #pragma unroll
  for (int r = 1; r < 8; r++) {
    int a = j * r;                                // < M
    float x = (float)a * (1.0f / (float)M);       // revolutions, exact
    float s = -__builtin_amdgcn_sinf(x);          // e^{-2 pi i x}
    float c =  __builtin_amdgcn_cosf(x);
    v[r] = cmulf(v[r], c, s);
  }
  #pragma unroll
  for (int r = 0; r < 8; r++) Zl[SWZ(base + j + STRIDE * r)] = v[r];
}

// Final pass: two radix-4 DFTs on contiguous slots [8t..8t+3], [8t+4..8t+7].
__device__ __forceinline__ void fft_pass4x2(float2* Zl, int t) {
  float2 v[8];
  #pragma unroll
  for (int p = 0; p < 8; p++) v[p] = Zl[SWZ(8 * t + p)];
  dft4i(v);
  dft4i(v + 4);
  #pragma unroll
  for (int p = 0; p < 8; p++) Zl[SWZ(8 * t + p)] = v[p];
}

// Chebyshev synthesis of 16 samples l = tid + 256k from 16 bins at cbase.
// g(l+256) = T g(l) - g(l-256), T = 2 cos(2 pi f/16). Seeds exact fp32.
__device__ __forceinline__ void synthc(const float4* CF, const float* CFf,
                                       int cbase, float tf, float* acc) {
  #pragma unroll
  for (int k = 0; k < 16; k++) acc[k] = 0.f;
  #pragma unroll 1
  for (int g = 0; g < 4; g++) {
    float u[4], v[4], T[4];
    #pragma unroll
    for (int j = 0; j < 4; j++) {
      float4 cf = CF[cbase + g * 4 + j];
      float f  = CFf[cbase + g * 4 + j];
      float x0 = f * tf * 2.44140625e-4f;     // f*tid/4096 rev, exact
      x0 -= floorf(x0);
      float c0 = __builtin_amdgcn_cosf(x0);
      float s0 = __builtin_amdgcn_sinf(x0);
      float G = fmaf(cf.x, c0, cf.y * s0);    // g(tid)
      float H = fmaf(cf.y, c0, -cf.x * s0);   // b cos - a sin
      u[j] = G;
      v[j] = fmaf(G, cf.z, -H * cf.w);        // g(tid - 256)
      T[j] = cf.z + cf.z;
    }
    #pragma unroll
    for (int k = 0; k < 16; k += 2) {
      #pragma unroll
      for (int j = 0; j < 4; j++) { acc[k] += u[j];     v[j] = fmaf(T[j], u[j], -v[j]); }
      #pragma unroll
      for (int j = 0; j < 4; j++) { acc[k + 1] += v[j]; u[j] = fmaf(T[j], v[j], -u[j]); }
    }
  }
}

// ---------------- fused real-FFT + top-k + synthesis kernel ----------------

__global__ __launch_bounds__(256, 4) void fourier_fused(
    const float2* __restrict__ X2, float2* __restrict__ O2) {
  __shared__ float2 Z[2048];        // 16 KB: one 2048-pt complex workspace
  __shared__ float4 CF[32];         // [ch*16+r] = (alpha, beta, cos_st, sin_st)
  __shared__ float  CFf[32];        // bin frequency f
  __shared__ float2 TK[4];          // per-wave top-k candidates

  const int tid = threadIdx.x;
  const int wv = tid >> 6;
  const int lane = tid & 63;
  // XCD-contiguous remap (bijective: 4096 blocks, 8 XCDs, 512 each):
  // 8 whole batches per XCD -> sibling channel-pair blocks of a batch
  // share that XCD's L2 lines for strided reads and partial-line writes.
  const int o = ((blockIdx.x & 7) << 9) + (blockIdx.x >> 3);
  const int b = o >> 6;
  const int q = o & 63;             // channel pair: channels 2q, 2q+1

  float* Zf = (float*)Z;
  const float inv = 2.44140625e-4f;  // 1/4096

  // ---- load: x[b, l, 2q..2q+1] = one float2. ch0 sample l goes to float
  // slot l of the complex buffer (even/odd packing == natural order);
  // ch1 parks in 16 regs (freed before synth).
  const float2* src = X2 + (size_t)b * 4096 * 64 + q;
  float park[16];
  #pragma unroll
  for (int k = 0; k < 16; k++) {
    int l = tid + 256 * k;
    float2 v = src[(size_t)l * 64];
    Zf[2 * SWZ(l >> 1) + (l & 1)] = v.x;
    park[k] = v.y;
  }
  __syncthreads();

  // ---- two sequential {FFT, untangle+top-16} halves over the same Z ----
  #pragma unroll 1
  for (int half = 0; half < 2; half++) {
    if (half) {                     // Z dead after top-k #0
      #pragma unroll
      for (int k = 0; k < 16; k++) {
        int l = tid + 256 * k;
        Zf[2 * SWZ(l >> 1) + (l & 1)] = park[k];
      }
      __syncthreads();
    }

    // forward 2048-pt FFT: radix 8,8,8 then 4x2. Slot map = slotOf().
    fft_pass8<256, 2048>(Z, 0, tid);
    __syncthreads();
    fft_pass8<32, 256>(Z, (tid >> 5) << 8, tid & 31);
    __syncthreads();
    fft_pass8<4, 32>(Z, (tid >> 2) << 5, tid & 3);
    __syncthreads();
    fft_pass4x2(Z, tid);
    __syncthreads();

    // ---- untangled magnitude scan: all 256 threads, 8 bins each.
    // X[f] = E + W^f O (W = e^{-2pi i f/4096}); store m2 = |2X|^2.
    float m2[8];
    #pragma unroll
    for (int k = 0; k < 8; k++) {
      int f = tid + (k << 8);
      float2 P = Z[SWZ(slotOf(f))];
      float2 Q = Z[SWZ(slotOf((2048 - f) & 2047))];
      float x = (float)f * inv;                  // < 0.5, exact
      float c = __builtin_amdgcn_cosf(x);
      float s = __builtin_amdgcn_sinf(x);
      float Sx = P.x + Q.x, Dy = P.y - Q.y;
      float Sy = P.y + Q.y, Dx = P.x - Q.x;
      float xr = Sx + c * Sy - s * Dx;           // 2 Re X
      float xi = Dy - c * Dx - s * Sy;           // 2 Im X
      m2[k] = xr * xr + xi * xi;
    }
    float m2x = -1.f;                            // Nyquist f=2048, tid 0
    if (tid == 0) {
      float2 P = Z[SWZ(0)];
      float t = P.x - P.y;                       // X[2048] = Re - Im
      m2x = 4.f * t * t;
    }

    // ---- 16 selection rounds, 4-wave cooperative ----
    for (int r = 0; r < 16; r++) {
      float bv = -1e30f; int bf = 0;
      #pragma unroll
      for (int k = 0; k < 8; k++) {
        int f = tid + (k << 8);
        if (m2[k] > bv) { bv = m2[k]; bf = f; }  // ascending: ties -> lower f
      }
      if (m2x > bv) { bv = m2x; bf = 2048; }
      #pragma unroll
      for (int off = 32; off; off >>= 1) {
        float ov = __shfl_down(bv, off);
        int   of = __shfl_down(bf, off);
        if (ov > bv || (ov == bv && of < bf)) { bv = ov; bf = of; }
      }
      if (lane == 0) TK[wv] = make_float2(bv, __int_as_float(bf));
      __syncthreads();
      bv = TK[0].x; bf = __float_as_int(TK[0].y);
      #pragma unroll
      for (int wI = 1; wI < 4; wI++) {
        float ov = TK[wI].x; int of = __float_as_int(TK[wI].y);
        if (ov > bv || (ov == bv && of < bf)) { bv = ov; bf = of; }
      }
      if (tid == r) {                            // capture coefficients
        float fv = (float)bf;
        float alpha, beta;
        if (bf == 2048) {
          float2 P = Z[SWZ(0)];
          alpha = inv * (P.x - P.y);
          beta = 0.f;
        } else {
          float2 P = Z[SWZ(slotOf(bf))];
          float2 Q = Z[SWZ(slotOf((2048 - bf) & 2047))];
          float x = fv * inv;
          float c = __builtin_amdgcn_cosf(x);
          float s = __builtin_amdgcn_sinf(x);
          float Sx = P.x + Q.x, Dy = P.y - Q.y;
          float Sy = P.y + Q.y, Dx = P.x - Q.x;
          float xr = 0.5f * (Sx + c * Sy - s * Dx);
          float xi = 0.5f * (Dy - c * Dx - s * Sy);
          float w = (bf == 0) ? inv : 2.f * inv;
          alpha = w * xr; beta = -w * xi;
        }
        float dxs = fv * 0.0625f;                // f*256/4096 = f/16 rev
        dxs -= floorf(dxs);
        float cd = __builtin_amdgcn_cosf(dxs);
        float sd = __builtin_amdgcn_sinf(dxs);
        CF[(half << 4) + r] = make_float4(alpha, beta, cd, sd);
        CFf[(half << 4) + r] = fv;
      }
      if (bf == 2048) {                          // knockout
        if (tid == 0) m2x = -2.f;
      } else if ((bf & 255) == tid) {
        int kk = bf >> 8;
        #pragma unroll
        for (int k = 0; k < 8; k++) if (k == kk) m2[k] = -2.f;
      }
      __syncthreads();                           // TK WAR + CF/Z ordering
    }
  }

  // ---- synthesis: 16 samples/thread/channel; ch0 staged through dead Z ----
  float acc[16];
  const float tf = (float)tid;
  synthc(CF, CFf, 0, tf, acc);
  float* Sf = (float*)Z;                          // 4096 floats, plain index
  #pragma unroll
  for (int k = 0; k < 16; k++) Sf[tid + 256 * k] = acc[k];
  synthc(CF, CFf, 16, tf, acc);

  // ---- store: float2 = both channels at one sample (same-thread Sf reads,
  // no barrier needed) ----
  float2* dst = O2 + (size_t)b * 4096 * 64 + q;
  #pragma unroll
  for (int k = 0; k < 16; k++) {
    int l = tid + 256 * k;
    dst[(size_t)l * 64] = make_float2(Sf[l], acc[k]);
  }
}

extern "C" void kernel_launch(void* const* d_in, const int* in_sizes, int n_in,
                              void* d_out, int out_size, void* d_ws, size_t ws_size,
                              hipStream_t stream) {
  (void)in_sizes; (void)n_in; (void)ws_size; (void)out_size; (void)d_ws;
  const float2* x = (const float2*)d_in[0];
  float2* out = (float2*)d_out;

  fourier_fused<<<dim3(64 * 64), dim3(256), 0, stream>>>(x, out);
}